// Round 1
// baseline (769.366 us; speedup 1.0000x reference)
//
#include <hip/hip_runtime.h>
#include <hip/hip_bf16.h>

typedef __bf16  bf16x8 __attribute__((ext_vector_type(8)));
typedef float   f32x4  __attribute__((ext_vector_type(4)));
typedef short   s16x8  __attribute__((ext_vector_type(8)));

typedef const __attribute__((address_space(1))) void g_void;
typedef __attribute__((address_space(3))) void l_void;

__device__ __forceinline__ short f2b(float x) {
    __hip_bfloat16 h = __float2bfloat16(x);
    return __builtin_bit_cast(short, h);
}

__device__ __forceinline__ f32x4 mfma16(s16x8 a, s16x8 b, f32x4 c) {
    return __builtin_amdgcn_mfma_f32_16x16x32_bf16(
        __builtin_bit_cast(bf16x8, a), __builtin_bit_cast(bf16x8, b), c, 0, 0, 0);
}

// ---------------- transpose + fp32 -> bf16 :  src [R,C] f32 -> dst [C,R] bf16
// grid (C/32, R/32, batch), block 256
__global__ __launch_bounds__(256) void transpose_bf16(
    const float* __restrict__ src, short* __restrict__ dst, int R, int C) {
    __shared__ float tile[32][33];
    src += (size_t)blockIdx.z * R * C;
    dst += (size_t)blockIdx.z * R * C;
    const int c0 = blockIdx.x * 32, r0 = blockIdx.y * 32;
    const int tx = threadIdx.x & 31, ty = threadIdx.x >> 5;   // ty 0..7
#pragma unroll
    for (int i = 0; i < 32; i += 8)
        tile[ty + i][tx] = src[(size_t)(r0 + ty + i) * C + c0 + tx];
    __syncthreads();
#pragma unroll
    for (int i = 0; i < 32; i += 8)
        dst[(size_t)(c0 + ty + i) * R + r0 + tx] = f2b(tile[tx][ty + i]);
}

// ---------------- concat q/k/v bias into [3072] f32
__global__ __launch_bounds__(256) void concat_bias(
    const float* __restrict__ bq, const float* __restrict__ bk,
    const float* __restrict__ bv, float* __restrict__ o) {
    int i = blockIdx.x * 256 + threadIdx.x;
    if (i < 1024)      o[i] = bq[i];
    else if (i < 2048) o[i] = bk[i - 1024];
    else if (i < 3072) o[i] = bv[i - 2048];
}

// ---------------- LayerNorm (D=1024) f32 in -> bf16 out. 1 block/row, 256 thr
__global__ __launch_bounds__(256) void ln_bf16(
    const float* __restrict__ x, const float* __restrict__ gamma,
    const float* __restrict__ beta, short* __restrict__ out) {
    __shared__ float red[8];
    const int row = blockIdx.x, tid = threadIdx.x;
    const float4 v = *(const float4*)(x + (size_t)row * 1024 + tid * 4);
    float s = v.x + v.y + v.z + v.w;
    float q = v.x * v.x + v.y * v.y + v.z * v.z + v.w * v.w;
#pragma unroll
    for (int off = 32; off > 0; off >>= 1) {
        s += __shfl_xor(s, off);
        q += __shfl_xor(q, off);
    }
    if ((tid & 63) == 0) { red[(tid >> 6) * 2] = s; red[(tid >> 6) * 2 + 1] = q; }
    __syncthreads();
    s = red[0] + red[2] + red[4] + red[6];
    q = red[1] + red[3] + red[5] + red[7];
    const float mu = s * (1.0f / 1024.0f);
    const float var = q * (1.0f / 1024.0f) - mu * mu;
    const float rs = rsqrtf(var + 1e-5f);
    const float4 g  = *(const float4*)(gamma + tid * 4);
    const float4 bt = *(const float4*)(beta + tid * 4);
    short4 o;
    o.x = f2b((v.x - mu) * rs * g.x + bt.x);
    o.y = f2b((v.y - mu) * rs * g.y + bt.y);
    o.z = f2b((v.z - mu) * rs * g.z + bt.z);
    o.w = f2b((v.w - mu) * rs * g.w + bt.w);
    *(short4*)(out + (size_t)row * 1024 + tid * 4) = o;
}

// ---------------- bf16 MFMA GEMM: C[M,N] = A[M,K] * Bt[N,K]^T (+ epilogue)
// 128x128 tile, BK=32, 4 waves (2x2), each wave 4x4 16x16x32 MFMA tiles.
// MODE 0: QKV scatter: out bf16 to [3][B,H,S,HD], bias added
// MODE 1: out f32 = acc + bias[col] + resid[row*N+col]
// MODE 2: out bf16 = gelu(acc + bias[col])
template <int MODE>
__global__ __launch_bounds__(256) void gemm_bf16(
    const short* __restrict__ A, const short* __restrict__ Bt,
    const float* __restrict__ bias, const float* __restrict__ resid,
    float* __restrict__ outf, short* __restrict__ outb,
    int M, int N, int K) {
    __shared__ __align__(16) short As[128 * 32];
    __shared__ __align__(16) short Bs[128 * 32];

    const int tid = threadIdx.x;
    const int wave = tid >> 6, lane = tid & 63;
    const int l16 = lane & 15, quad = lane >> 4;
    const int wm = wave & 1, wn = wave >> 1;
    const int m0 = blockIdx.y * 128, n0 = blockIdx.x * 128;
    const int lrow = lane >> 2;        // 0..15
    const int lcol = (lane & 3) * 8;   // 16B chunk within 32-elem row

    f32x4 acc[4][4] = {};

    for (int kk = 0; kk < K; kk += 32) {
#pragma unroll
        for (int i = 0; i < 2; ++i) {
            const int r = wave * 32 + i * 16 + lrow;
            const short* ga = A + (size_t)(m0 + r) * K + kk + lcol;
            short* la = &As[(wave * 32 + i * 16) * 32];
            __builtin_amdgcn_global_load_lds((g_void*)ga, (l_void*)la, 16, 0, 0);
            const short* gb = Bt + (size_t)(n0 + r) * K + kk + lcol;
            short* lb = &Bs[(wave * 32 + i * 16) * 32];
            __builtin_amdgcn_global_load_lds((g_void*)gb, (l_void*)lb, 16, 0, 0);
        }
        __syncthreads();
        s16x8 a[4], b[4];
#pragma unroll
        for (int t = 0; t < 4; ++t) {
            a[t] = *(const s16x8*)&As[(wm * 64 + t * 16 + l16) * 32 + quad * 8];
            b[t] = *(const s16x8*)&Bs[(wn * 64 + t * 16 + l16) * 32 + quad * 8];
        }
#pragma unroll
        for (int mt = 0; mt < 4; ++mt)
#pragma unroll
            for (int nt = 0; nt < 4; ++nt)
                acc[mt][nt] = mfma16(a[mt], b[nt], acc[mt][nt]);
        __syncthreads();
    }

#pragma unroll
    for (int mt = 0; mt < 4; ++mt) {
#pragma unroll
        for (int nt = 0; nt < 4; ++nt) {
            const int row = m0 + wm * 64 + mt * 16 + quad * 4;
            const int col = n0 + wn * 64 + nt * 16 + l16;
            const float bc = bias[col];
#pragma unroll
            for (int r = 0; r < 4; ++r) {
                float v = acc[mt][nt][r] + bc;
                const size_t rr = (size_t)(row + r);
                if (MODE == 0) {
                    const int sel = col >> 10, within = col & 1023;
                    const int h = within >> 6, hd = within & 63;
                    const size_t bidx = rr >> 11, sp = rr & 2047;
                    outb[(size_t)sel * (8192ull * 1024) +
                         ((bidx * 16 + h) * 2048 + sp) * 64 + hd] = f2b(v);
                } else if (MODE == 1) {
                    v += resid[rr * N + col];
                    outf[rr * N + col] = v;
                } else {
                    v = 0.5f * v * (1.0f + erff(v * 0.70710678118654752f));
                    outb[rr * (size_t)N + col] = f2b(v);
                }
            }
        }
    }
}

// ---------------- causal flash attention
// Q,K,V bf16 [B,H,S,HD]; O bf16 [B,S,H*HD]. One block per (b,h,64-row Q tile).
__global__ __launch_bounds__(256) void attn_kernel(
    const short* __restrict__ Q, const short* __restrict__ K,
    const short* __restrict__ V, short* __restrict__ O) {
    const int bid = blockIdx.x;
    const int qt = bid & 31;           // S/64 = 32
    const int h  = (bid >> 5) & 15;
    const int b  = bid >> 9;
    const int q0 = qt * 64;
    const int tid = threadIdx.x, wave = tid >> 6, lane = tid & 63;
    const int l16 = lane & 15, quad = lane >> 4;

    __shared__ __align__(16) short Ks[64 * 72];
    __shared__ __align__(16) short Vt[64 * 72];
    __shared__ __align__(16) short Ps[4][16 * 72];

    const size_t bh = ((size_t)b * 16 + h) * 2048 * 64;

    // Q fragments: wave handles rows q0+wave*16 .. +15
    s16x8 aq0, aq1;
    {
        const short* qrow = Q + bh + (size_t)(q0 + wave * 16 + l16) * 64;
        aq0 = *(const s16x8*)(qrow + quad * 8);
        aq1 = *(const s16x8*)(qrow + 32 + quad * 8);
    }
    f32x4 oacc[4] = {};
    float mrow[4], lrow[4];
#pragma unroll
    for (int r = 0; r < 4; ++r) { mrow[r] = -1e30f; lrow[r] = 0.0f; }
    const int row_g = q0 + wave * 16 + quad * 4;   // + r

    for (int j = 0; j <= qt; ++j) {
        // stage K tile [t][hd] and transposed V tile [hd][t]
        {
            const int r = tid >> 2, qtr = tid & 3;
            const short* krow = K + bh + (size_t)(j * 64 + r) * 64 + qtr * 16;
            s16x8 k0 = *(const s16x8*)(krow);
            s16x8 k1 = *(const s16x8*)(krow + 8);
            *(s16x8*)&Ks[r * 72 + qtr * 16]     = k0;
            *(s16x8*)&Ks[r * 72 + qtr * 16 + 8] = k1;
            const short* vrow = V + bh + (size_t)(j * 64 + r) * 64 + qtr * 16;
            s16x8 v0 = *(const s16x8*)(vrow);
            s16x8 v1 = *(const s16x8*)(vrow + 8);
#pragma unroll
            for (int e = 0; e < 8; ++e) Vt[(qtr * 16 + e) * 72 + r]     = v0[e];
#pragma unroll
            for (int e = 0; e < 8; ++e) Vt[(qtr * 16 + 8 + e) * 72 + r] = v1[e];
        }
        __syncthreads();

        // S = Q K^T (16x64 strip per wave)
        float st[4][4];
#pragma unroll
        for (int nt = 0; nt < 4; ++nt) {
            s16x8 bk0 = *(const s16x8*)&Ks[(nt * 16 + l16) * 72 + quad * 8];
            s16x8 bk1 = *(const s16x8*)&Ks[(nt * 16 + l16) * 72 + 32 + quad * 8];
            f32x4 c = {};
            c = mfma16(aq0, bk0, c);
            c = mfma16(aq1, bk1, c);
#pragma unroll
            for (int r = 0; r < 4; ++r) st[nt][r] = c[r];
        }
        // scale + causal mask (only diagonal tile is partial)
        const bool diag = (j == qt);
#pragma unroll
        for (int nt = 0; nt < 4; ++nt)
#pragma unroll
            for (int r = 0; r < 4; ++r) {
                float s = st[nt][r] * 0.125f;
                if (diag) {
                    const int t = j * 64 + nt * 16 + l16;
                    if (t > row_g + r) s = -1e30f;
                }
                st[nt][r] = s;
            }
        // online softmax
        float mx[4];
#pragma unroll
        for (int r = 0; r < 4; ++r)
            mx[r] = fmaxf(fmaxf(st[0][r], st[1][r]), fmaxf(st[2][r], st[3][r]));
#pragma unroll
        for (int off = 1; off < 16; off <<= 1)
#pragma unroll
            for (int r = 0; r < 4; ++r) mx[r] = fmaxf(mx[r], __shfl_xor(mx[r], off));
        float alpha[4], rs[4];
#pragma unroll
        for (int r = 0; r < 4; ++r) {
            const float mn = fmaxf(mrow[r], mx[r]);
            alpha[r] = __expf(mrow[r] - mn);
            mrow[r] = mn;
            rs[r] = 0.0f;
        }
#pragma unroll
        for (int nt = 0; nt < 4; ++nt)
#pragma unroll
            for (int r = 0; r < 4; ++r) {
                const float p = __expf(st[nt][r] - mrow[r]);
                st[nt][r] = p;
                rs[r] += p;
            }
#pragma unroll
        for (int off = 1; off < 16; off <<= 1)
#pragma unroll
            for (int r = 0; r < 4; ++r) rs[r] += __shfl_xor(rs[r], off);
#pragma unroll
        for (int r = 0; r < 4; ++r) lrow[r] = lrow[r] * alpha[r] + rs[r];
#pragma unroll
        for (int nt = 0; nt < 4; ++nt)
#pragma unroll
            for (int r = 0; r < 4; ++r) oacc[nt][r] *= alpha[r];

        // P: C-layout -> A-layout via per-wave LDS
#pragma unroll
        for (int nt = 0; nt < 4; ++nt)
#pragma unroll
            for (int r = 0; r < 4; ++r)
                Ps[wave][(quad * 4 + r) * 72 + nt * 16 + l16] = f2b(st[nt][r]);
        asm volatile("s_waitcnt lgkmcnt(0)" ::: "memory");
        s16x8 ap0 = *(const s16x8*)&Ps[wave][l16 * 72 + quad * 8];
        s16x8 ap1 = *(const s16x8*)&Ps[wave][l16 * 72 + 32 + quad * 8];

        // O += P V
#pragma unroll
        for (int nt = 0; nt < 4; ++nt) {
            s16x8 bv0 = *(const s16x8*)&Vt[(nt * 16 + l16) * 72 + quad * 8];
            s16x8 bv1 = *(const s16x8*)&Vt[(nt * 16 + l16) * 72 + 32 + quad * 8];
            oacc[nt] = mfma16(ap0, bv0, oacc[nt]);
            oacc[nt] = mfma16(ap1, bv1, oacc[nt]);
        }
        __syncthreads();
    }

    // epilogue: O[b, s, h*64+hd] bf16
#pragma unroll
    for (int nt = 0; nt < 4; ++nt)
#pragma unroll
        for (int r = 0; r < 4; ++r) {
            const int row = q0 + wave * 16 + quad * 4 + r;
            const float o = oacc[nt][r] / lrow[r];
            O[((size_t)b * 2048 + row) * 1024 + h * 64 + nt * 16 + l16] = f2b(o);
        }
}

extern "C" void kernel_launch(void* const* d_in, const int* in_sizes, int n_in,
                              void* d_out, int out_size, void* d_ws, size_t ws_size,
                              hipStream_t stream) {
    const float* x     = (const float*)d_in[0];
    const float* Wq    = (const float*)d_in[1];
    const float* Wk    = (const float*)d_in[2];
    const float* Wv    = (const float*)d_in[3];
    const float* bq    = (const float*)d_in[4];
    const float* bk    = (const float*)d_in[5];
    const float* bv    = (const float*)d_in[6];
    const float* Wo    = (const float*)d_in[7];
    const float* bo    = (const float*)d_in[8];
    const float* W1    = (const float*)d_in[9];
    const float* b1    = (const float*)d_in[10];
    const float* W2    = (const float*)d_in[11];
    const float* b2    = (const float*)d_in[12];
    const float* gamma = (const float*)d_in[13];
    const float* beta  = (const float*)d_in[14];
    float* out = (float*)d_out;

    char* ws = (char*)d_ws;
    size_t off = 0;
    auto alloc = [&](size_t bytes) -> char* {
        char* p = ws + off;
        off += (bytes + 255) & ~(size_t)255;
        return p;
    };
    short* h1    = (short*)alloc(8192ull * 1024 * 2);
    short* btqkv = (short*)alloc(3072ull * 1024 * 2);
    short* btwo  = (short*)alloc(1024ull * 1024 * 2);
    short* btw1  = (short*)alloc(4096ull * 1024 * 2);
    short* btw2  = (short*)alloc(1024ull * 4096 * 2);
    float* bqkv  = (float*)alloc(3072ull * 4);
    short* qkv   = (short*)alloc(3ull * 8192 * 1024 * 2);
    short* aout  = (short*)alloc(8192ull * 1024 * 2);
    float* x2    = (float*)alloc(8192ull * 1024 * 4);
    short* h2    = (short*)alloc(8192ull * 1024 * 2);
    short* m1    = (short*)alloc(8192ull * 4096 * 2);

    // weight prep: Bt[N][K] bf16 layouts
    transpose_bf16<<<dim3(2, 32, 16), 256, 0, stream>>>(Wq, btqkv, 1024, 64);
    transpose_bf16<<<dim3(2, 32, 16), 256, 0, stream>>>(Wk, btqkv + 1024ull * 1024, 1024, 64);
    transpose_bf16<<<dim3(2, 32, 16), 256, 0, stream>>>(Wv, btqkv + 2ull * 1024 * 1024, 1024, 64);
    transpose_bf16<<<dim3(32, 32, 1), 256, 0, stream>>>(Wo, btwo, 1024, 1024);
    transpose_bf16<<<dim3(128, 32, 1), 256, 0, stream>>>(W1, btw1, 1024, 4096);
    transpose_bf16<<<dim3(32, 128, 1), 256, 0, stream>>>(W2, btw2, 4096, 1024);
    concat_bias<<<12, 256, 0, stream>>>(bq, bk, bv, bqkv);

    // LN1
    ln_bf16<<<8192, 256, 0, stream>>>(x, gamma, beta, h1);
    // QKV projection
    gemm_bf16<0><<<dim3(24, 64), 256, 0, stream>>>(
        h1, btqkv, bqkv, nullptr, nullptr, qkv, 8192, 3072, 1024);
    // attention
    attn_kernel<<<2048, 256, 0, stream>>>(
        qkv, qkv + 8192ull * 1024, qkv + 2ull * 8192 * 1024, aout);
    // Wo + residual -> x2 (f32)
    gemm_bf16<1><<<dim3(8, 64), 256, 0, stream>>>(
        aout, btwo, bo, x, x2, nullptr, 8192, 1024, 1024);
    // LN2
    ln_bf16<<<8192, 256, 0, stream>>>(x2, gamma, beta, h2);
    // MLP1 + GELU
    gemm_bf16<2><<<dim3(32, 64), 256, 0, stream>>>(
        h2, btw1, b1, nullptr, nullptr, m1, 8192, 4096, 1024);
    // MLP2 + residual -> out (f32)
    gemm_bf16<1><<<dim3(8, 64), 256, 0, stream>>>(
        m1, btw2, b2, x2, out, nullptr, 8192, 1024, 4096);
}

// Round 2
// 665.435 us; speedup vs baseline: 1.1562x; 1.1562x over previous
//
#include <hip/hip_runtime.h>
#include <hip/hip_bf16.h>

typedef __bf16  bf16x8 __attribute__((ext_vector_type(8)));
typedef float   f32x4  __attribute__((ext_vector_type(4)));
typedef short   s16x8  __attribute__((ext_vector_type(8)));

typedef const __attribute__((address_space(1))) void g_void;
typedef __attribute__((address_space(3))) void l_void;

__device__ __forceinline__ short f2b(float x) {
    __hip_bfloat16 h = __float2bfloat16(x);
    return __builtin_bit_cast(short, h);
}

__device__ __forceinline__ f32x4 mfma16(s16x8 a, s16x8 b, f32x4 c) {
    return __builtin_amdgcn_mfma_f32_16x16x32_bf16(
        __builtin_bit_cast(bf16x8, a), __builtin_bit_cast(bf16x8, b), c, 0, 0, 0);
}

// ---------------- transpose + fp32 -> bf16 :  src [R,C] f32 -> dst [C,R] bf16
__global__ __launch_bounds__(256) void transpose_bf16(
    const float* __restrict__ src, short* __restrict__ dst, int R, int C) {
    __shared__ float tile[32][33];
    src += (size_t)blockIdx.z * R * C;
    dst += (size_t)blockIdx.z * R * C;
    const int c0 = blockIdx.x * 32, r0 = blockIdx.y * 32;
    const int tx = threadIdx.x & 31, ty = threadIdx.x >> 5;
#pragma unroll
    for (int i = 0; i < 32; i += 8)
        tile[ty + i][tx] = src[(size_t)(r0 + ty + i) * C + c0 + tx];
    __syncthreads();
#pragma unroll
    for (int i = 0; i < 32; i += 8)
        dst[(size_t)(c0 + ty + i) * R + r0 + tx] = f2b(tile[tx][ty + i]);
}

// ---------------- bf16 transpose per (b,h): src [BH][2048][64] -> dst [BH][64][2048]
__global__ __launch_bounds__(256) void transpose_v_bf16(
    const short* __restrict__ src, short* __restrict__ dst) {
    __shared__ short tile[32][34];
    const int bh = blockIdx.z;
    src += (size_t)bh * 2048 * 64;
    dst += (size_t)bh * 2048 * 64;
    const int c0 = blockIdx.x * 32;   // hd
    const int r0 = blockIdx.y * 32;   // s
    const int tx = threadIdx.x & 31, ty = threadIdx.x >> 5;
#pragma unroll
    for (int i = 0; i < 32; i += 8)
        tile[ty + i][tx] = src[(size_t)(r0 + ty + i) * 64 + c0 + tx];
    __syncthreads();
#pragma unroll
    for (int i = 0; i < 32; i += 8)
        dst[(size_t)(c0 + ty + i) * 2048 + r0 + tx] = tile[tx][ty + i];
}

// ---------------- concat q/k/v bias into [3072] f32
__global__ __launch_bounds__(256) void concat_bias(
    const float* __restrict__ bq, const float* __restrict__ bk,
    const float* __restrict__ bv, float* __restrict__ o) {
    int i = blockIdx.x * 256 + threadIdx.x;
    if (i < 1024)      o[i] = bq[i];
    else if (i < 2048) o[i] = bk[i - 1024];
    else if (i < 3072) o[i] = bv[i - 2048];
}

// ---------------- LayerNorm (D=1024) f32 in -> bf16 out. 1 block/row, 256 thr
__global__ __launch_bounds__(256) void ln_bf16(
    const float* __restrict__ x, const float* __restrict__ gamma,
    const float* __restrict__ beta, short* __restrict__ out) {
    __shared__ float red[8];
    const int row = blockIdx.x, tid = threadIdx.x;
    const float4 v = *(const float4*)(x + (size_t)row * 1024 + tid * 4);
    float s = v.x + v.y + v.z + v.w;
    float q = v.x * v.x + v.y * v.y + v.z * v.z + v.w * v.w;
#pragma unroll
    for (int off = 32; off > 0; off >>= 1) {
        s += __shfl_xor(s, off);
        q += __shfl_xor(q, off);
    }
    if ((tid & 63) == 0) { red[(tid >> 6) * 2] = s; red[(tid >> 6) * 2 + 1] = q; }
    __syncthreads();
    s = red[0] + red[2] + red[4] + red[6];
    q = red[1] + red[3] + red[5] + red[7];
    const float mu = s * (1.0f / 1024.0f);
    const float var = q * (1.0f / 1024.0f) - mu * mu;
    const float rs = rsqrtf(var + 1e-5f);
    const float4 g  = *(const float4*)(gamma + tid * 4);
    const float4 bt = *(const float4*)(beta + tid * 4);
    short4 o;
    o.x = f2b((v.x - mu) * rs * g.x + bt.x);
    o.y = f2b((v.y - mu) * rs * g.y + bt.y);
    o.z = f2b((v.z - mu) * rs * g.z + bt.z);
    o.w = f2b((v.w - mu) * rs * g.w + bt.w);
    *(short4*)(out + (size_t)row * 1024 + tid * 4) = o;
}

// ---------------- bf16 MFMA GEMM: C[M,N] = A[M,K] * Bt[N,K]^T (+ epilogue)
template <int MODE>
__global__ __launch_bounds__(256) void gemm_bf16(
    const short* __restrict__ A, const short* __restrict__ Bt,
    const float* __restrict__ bias, const float* __restrict__ resid,
    float* __restrict__ outf, short* __restrict__ outb,
    int M, int N, int K) {
    __shared__ __align__(16) short As[128 * 32];
    __shared__ __align__(16) short Bs[128 * 32];

    const int tid = threadIdx.x;
    const int wave = tid >> 6, lane = tid & 63;
    const int l16 = lane & 15, quad = lane >> 4;
    const int wm = wave & 1, wn = wave >> 1;
    const int m0 = blockIdx.y * 128, n0 = blockIdx.x * 128;
    const int lrow = lane >> 2;
    const int lcol = (lane & 3) * 8;

    f32x4 acc[4][4] = {};

    for (int kk = 0; kk < K; kk += 32) {
#pragma unroll
        for (int i = 0; i < 2; ++i) {
            const int r = wave * 32 + i * 16 + lrow;
            const short* ga = A + (size_t)(m0 + r) * K + kk + lcol;
            short* la = &As[(wave * 32 + i * 16) * 32];
            __builtin_amdgcn_global_load_lds((g_void*)ga, (l_void*)la, 16, 0, 0);
            const short* gb = Bt + (size_t)(n0 + r) * K + kk + lcol;
            short* lb = &Bs[(wave * 32 + i * 16) * 32];
            __builtin_amdgcn_global_load_lds((g_void*)gb, (l_void*)lb, 16, 0, 0);
        }
        __syncthreads();
        s16x8 a[4], b[4];
#pragma unroll
        for (int t = 0; t < 4; ++t) {
            a[t] = *(const s16x8*)&As[(wm * 64 + t * 16 + l16) * 32 + quad * 8];
            b[t] = *(const s16x8*)&Bs[(wn * 64 + t * 16 + l16) * 32 + quad * 8];
        }
#pragma unroll
        for (int mt = 0; mt < 4; ++mt)
#pragma unroll
            for (int nt = 0; nt < 4; ++nt)
                acc[mt][nt] = mfma16(a[mt], b[nt], acc[mt][nt]);
        __syncthreads();
    }

#pragma unroll
    for (int mt = 0; mt < 4; ++mt) {
#pragma unroll
        for (int nt = 0; nt < 4; ++nt) {
            const int row = m0 + wm * 64 + mt * 16 + quad * 4;
            const int col = n0 + wn * 64 + nt * 16 + l16;
            const float bc = bias[col];
#pragma unroll
            for (int r = 0; r < 4; ++r) {
                float v = acc[mt][nt][r] + bc;
                const size_t rr = (size_t)(row + r);
                if (MODE == 0) {
                    const int sel = col >> 10, within = col & 1023;
                    const int h = within >> 6, hd = within & 63;
                    const size_t bidx = rr >> 11, sp = rr & 2047;
                    outb[(size_t)sel * (8192ull * 1024) +
                         ((bidx * 16 + h) * 2048 + sp) * 64 + hd] = f2b(v);
                } else if (MODE == 1) {
                    v += resid[rr * N + col];
                    outf[rr * N + col] = v;
                } else {
                    v = 0.5f * v * (1.0f + erff(v * 0.70710678118654752f));
                    outb[rr * (size_t)N + col] = f2b(v);
                }
            }
        }
    }
}

// ---------------- causal flash attention (balanced pairing, pre-transposed V)
// Q,K bf16 [B,H,S,HD]; Vt bf16 [B,H,HD,S]; O bf16 [B,S,H*HD].
// Block p handles Q-tiles {p, 31-p} sequentially -> 33 K-tile iters each block.
__global__ __launch_bounds__(256) void attn_kernel(
    const short* __restrict__ Q, const short* __restrict__ K,
    const short* __restrict__ Vt, short* __restrict__ O) {
    const int bid = blockIdx.x;
    const int p = bid & 15;
    const int h = (bid >> 4) & 15;
    const int b = bid >> 8;
    const int tid = threadIdx.x, wave = tid >> 6, lane = tid & 63;
    const int l16 = lane & 15, quad = lane >> 4;

    __shared__ __align__(16) short Ks[64 * 72];
    __shared__ __align__(16) short Vts[64 * 72];
    __shared__ __align__(16) short Ps[4][16 * 72];

    const size_t bh = ((size_t)b * 16 + h) * (2048ull * 64);
    const int srow = tid >> 2;          // 0..63
    const int sseg = (tid & 3) * 16;    // 0,16,32,48
    const float SC = 0.125f * 1.44269504088896f;   // 1/sqrt(64) * log2(e)

    for (int pass = 0; pass < 2; ++pass) {
        const int qt = pass ? (31 - p) : p;
        const int q0 = qt * 64;

        const short* qrow = Q + bh + (size_t)(q0 + wave * 16 + l16) * 64;
        s16x8 aq0 = *(const s16x8*)(qrow + quad * 8);
        s16x8 aq1 = *(const s16x8*)(qrow + 32 + quad * 8);

        f32x4 oacc[4] = {};
        float mrow[4], lsum[4];
#pragma unroll
        for (int r = 0; r < 4; ++r) { mrow[r] = -1e30f; lsum[r] = 0.0f; }
        const int row_g = q0 + wave * 16 + quad * 4;

        for (int j = 0; j <= qt; ++j) {
            // issue global loads for this tile before the barrier
            const short* kg = K + bh + (size_t)(j * 64 + srow) * 64 + sseg;
            s16x8 k0 = *(const s16x8*)kg;
            s16x8 k1 = *(const s16x8*)(kg + 8);
            const short* vg = Vt + bh + (size_t)srow * 2048 + j * 64 + sseg;
            s16x8 v0 = *(const s16x8*)vg;
            s16x8 v1 = *(const s16x8*)(vg + 8);
            __syncthreads();            // prior iteration's reads complete
            *(s16x8*)&Ks[srow * 72 + sseg]      = k0;
            *(s16x8*)&Ks[srow * 72 + sseg + 8]  = k1;
            *(s16x8*)&Vts[srow * 72 + sseg]     = v0;
            *(s16x8*)&Vts[srow * 72 + sseg + 8] = v1;
            __syncthreads();

            // S = Q K^T (16x64 strip per wave), in log2 domain scale
            float st[4][4];
#pragma unroll
            for (int nt = 0; nt < 4; ++nt) {
                s16x8 bk0 = *(const s16x8*)&Ks[(nt * 16 + l16) * 72 + quad * 8];
                s16x8 bk1 = *(const s16x8*)&Ks[(nt * 16 + l16) * 72 + 32 + quad * 8];
                f32x4 c = {};
                c = mfma16(aq0, bk0, c);
                c = mfma16(aq1, bk1, c);
#pragma unroll
                for (int r = 0; r < 4; ++r) st[nt][r] = c[r];
            }
            const bool diag = (j == qt);
#pragma unroll
            for (int nt = 0; nt < 4; ++nt)
#pragma unroll
                for (int r = 0; r < 4; ++r) {
                    float s = st[nt][r] * SC;
                    if (diag) {
                        const int t = j * 64 + nt * 16 + l16;
                        if (t > row_g + r) s = -1e30f;
                    }
                    st[nt][r] = s;
                }
            // online softmax (base-2 domain)
            float mx[4];
#pragma unroll
            for (int r = 0; r < 4; ++r)
                mx[r] = fmaxf(fmaxf(st[0][r], st[1][r]), fmaxf(st[2][r], st[3][r]));
#pragma unroll
            for (int off = 1; off < 16; off <<= 1)
#pragma unroll
                for (int r = 0; r < 4; ++r) mx[r] = fmaxf(mx[r], __shfl_xor(mx[r], off));
            float alpha[4], rs[4];
#pragma unroll
            for (int r = 0; r < 4; ++r) {
                const float mn = fmaxf(mrow[r], mx[r]);
                alpha[r] = exp2f(mrow[r] - mn);
                mrow[r] = mn;
                rs[r] = 0.0f;
            }
#pragma unroll
            for (int nt = 0; nt < 4; ++nt)
#pragma unroll
                for (int r = 0; r < 4; ++r) {
                    const float pr = exp2f(st[nt][r] - mrow[r]);
                    st[nt][r] = pr;
                    rs[r] += pr;
                }
#pragma unroll
            for (int off = 1; off < 16; off <<= 1)
#pragma unroll
                for (int r = 0; r < 4; ++r) rs[r] += __shfl_xor(rs[r], off);
#pragma unroll
            for (int r = 0; r < 4; ++r) lsum[r] = lsum[r] * alpha[r] + rs[r];
#pragma unroll
            for (int nt = 0; nt < 4; ++nt)
#pragma unroll
                for (int r = 0; r < 4; ++r) oacc[nt][r] *= alpha[r];

            // P: C-layout -> A-layout via per-wave LDS
#pragma unroll
            for (int nt = 0; nt < 4; ++nt)
#pragma unroll
                for (int r = 0; r < 4; ++r)
                    Ps[wave][(quad * 4 + r) * 72 + nt * 16 + l16] = f2b(st[nt][r]);
            asm volatile("s_waitcnt lgkmcnt(0)" ::: "memory");
            s16x8 ap0 = *(const s16x8*)&Ps[wave][l16 * 72 + quad * 8];
            s16x8 ap1 = *(const s16x8*)&Ps[wave][l16 * 72 + 32 + quad * 8];

            // O += P V
#pragma unroll
            for (int nt = 0; nt < 4; ++nt) {
                s16x8 bv0 = *(const s16x8*)&Vts[(nt * 16 + l16) * 72 + quad * 8];
                s16x8 bv1 = *(const s16x8*)&Vts[(nt * 16 + l16) * 72 + 32 + quad * 8];
                oacc[nt] = mfma16(ap0, bv0, oacc[nt]);
                oacc[nt] = mfma16(ap1, bv1, oacc[nt]);
            }
        }
        __syncthreads();   // protect LDS before next pass restages

        // epilogue: O[b, s, h*64+hd] bf16
        float inv[4];
#pragma unroll
        for (int r = 0; r < 4; ++r) inv[r] = 1.0f / lsum[r];
#pragma unroll
        for (int nt = 0; nt < 4; ++nt)
#pragma unroll
            for (int r = 0; r < 4; ++r) {
                const int row = q0 + wave * 16 + quad * 4 + r;
                O[((size_t)b * 2048 + row) * 1024 + h * 64 + nt * 16 + l16] =
                    f2b(oacc[nt][r] * inv[r]);
            }
    }
}

extern "C" void kernel_launch(void* const* d_in, const int* in_sizes, int n_in,
                              void* d_out, int out_size, void* d_ws, size_t ws_size,
                              hipStream_t stream) {
    const float* x     = (const float*)d_in[0];
    const float* Wq    = (const float*)d_in[1];
    const float* Wk    = (const float*)d_in[2];
    const float* Wv    = (const float*)d_in[3];
    const float* bq    = (const float*)d_in[4];
    const float* bk    = (const float*)d_in[5];
    const float* bv    = (const float*)d_in[6];
    const float* Wo    = (const float*)d_in[7];
    const float* bo    = (const float*)d_in[8];
    const float* W1    = (const float*)d_in[9];
    const float* b1    = (const float*)d_in[10];
    const float* W2    = (const float*)d_in[11];
    const float* b2    = (const float*)d_in[12];
    const float* gamma = (const float*)d_in[13];
    const float* beta  = (const float*)d_in[14];
    float* out = (float*)d_out;

    char* ws = (char*)d_ws;
    size_t off = 0;
    auto alloc = [&](size_t bytes) -> char* {
        char* p = ws + off;
        off += (bytes + 255) & ~(size_t)255;
        return p;
    };
    short* h1    = (short*)alloc(8192ull * 1024 * 2);
    short* btqkv = (short*)alloc(3072ull * 1024 * 2);
    short* btwo  = (short*)alloc(1024ull * 1024 * 2);
    short* btw1  = (short*)alloc(4096ull * 1024 * 2);
    short* btw2  = (short*)alloc(1024ull * 4096 * 2);
    float* bqkv  = (float*)alloc(3072ull * 4);
    short* qkv   = (short*)alloc(3ull * 8192 * 1024 * 2);
    short* vt    = (short*)alloc(8192ull * 1024 * 2);
    short* aout  = (short*)alloc(8192ull * 1024 * 2);
    float* x2    = (float*)alloc(8192ull * 1024 * 4);
    short* h2    = (short*)alloc(8192ull * 1024 * 2);
    short* m1    = (short*)alloc(8192ull * 4096 * 2);

    // weight prep
    transpose_bf16<<<dim3(2, 32, 16), 256, 0, stream>>>(Wq, btqkv, 1024, 64);
    transpose_bf16<<<dim3(2, 32, 16), 256, 0, stream>>>(Wk, btqkv + 1024ull * 1024, 1024, 64);
    transpose_bf16<<<dim3(2, 32, 16), 256, 0, stream>>>(Wv, btqkv + 2ull * 1024 * 1024, 1024, 64);
    transpose_bf16<<<dim3(32, 32, 1), 256, 0, stream>>>(Wo, btwo, 1024, 1024);
    transpose_bf16<<<dim3(128, 32, 1), 256, 0, stream>>>(W1, btw1, 1024, 4096);
    transpose_bf16<<<dim3(32, 128, 1), 256, 0, stream>>>(W2, btw2, 4096, 1024);
    concat_bias<<<12, 256, 0, stream>>>(bq, bk, bv, bqkv);

    // LN1
    ln_bf16<<<8192, 256, 0, stream>>>(x, gamma, beta, h1);
    // QKV projection
    gemm_bf16<0><<<dim3(24, 64), 256, 0, stream>>>(
        h1, btqkv, bqkv, nullptr, nullptr, qkv, 8192, 3072, 1024);
    // V -> Vt [B,H,HD,S]
    transpose_v_bf16<<<dim3(2, 64, 64), 256, 0, stream>>>(
        qkv + 2ull * 8192 * 1024, vt);
    // attention
    attn_kernel<<<1024, 256, 0, stream>>>(
        qkv, qkv + 8192ull * 1024, vt, aout);
    // Wo + residual -> x2 (f32)
    gemm_bf16<1><<<dim3(8, 64), 256, 0, stream>>>(
        aout, btwo, bo, x, x2, nullptr, 8192, 1024, 1024);
    // LN2
    ln_bf16<<<8192, 256, 0, stream>>>(x2, gamma, beta, h2);
    // MLP1 + GELU
    gemm_bf16<2><<<dim3(32, 64), 256, 0, stream>>>(
        h2, btw1, b1, nullptr, nullptr, m1, 8192, 4096, 1024);
    // MLP2 + residual -> out (f32)
    gemm_bf16<1><<<dim3(8, 64), 256, 0, stream>>>(
        m1, btw2, b2, x2, out, nullptr, 8192, 1024, 4096);
}

// Round 3
// 647.042 us; speedup vs baseline: 1.1891x; 1.0284x over previous
//
#include <hip/hip_runtime.h>
#include <hip/hip_bf16.h>

typedef __bf16  bf16x8 __attribute__((ext_vector_type(8)));
typedef float   f32x4  __attribute__((ext_vector_type(4)));
typedef short   s16x8  __attribute__((ext_vector_type(8)));

typedef const __attribute__((address_space(1))) void g_void;
typedef __attribute__((address_space(3))) void l_void;

__device__ __forceinline__ short f2b(float x) {
    __hip_bfloat16 h = __float2bfloat16(x);
    return __builtin_bit_cast(short, h);
}

// pack two floats to bf16 pair in one int (lo | hi<<16)
__device__ __forceinline__ int pk2(float lo, float hi) {
    return (int)(unsigned short)f2b(lo) | ((int)f2b(hi) << 16);
}

__device__ __forceinline__ f32x4 mfma16(s16x8 a, s16x8 b, f32x4 c) {
    return __builtin_amdgcn_mfma_f32_16x16x32_bf16(
        __builtin_bit_cast(bf16x8, a), __builtin_bit_cast(bf16x8, b), c, 0, 0, 0);
}

// ---------------- transpose + fp32 -> bf16 :  src [R,C] f32 -> dst [C,R] bf16
__global__ __launch_bounds__(256) void transpose_bf16(
    const float* __restrict__ src, short* __restrict__ dst, int R, int C) {
    __shared__ float tile[32][33];
    src += (size_t)blockIdx.z * R * C;
    dst += (size_t)blockIdx.z * R * C;
    const int c0 = blockIdx.x * 32, r0 = blockIdx.y * 32;
    const int tx = threadIdx.x & 31, ty = threadIdx.x >> 5;
#pragma unroll
    for (int i = 0; i < 32; i += 8)
        tile[ty + i][tx] = src[(size_t)(r0 + ty + i) * C + c0 + tx];
    __syncthreads();
#pragma unroll
    for (int i = 0; i < 32; i += 8)
        dst[(size_t)(c0 + ty + i) * R + r0 + tx] = f2b(tile[tx][ty + i]);
}

// ---------------- bf16 transpose per (b,h): src [BH][2048][64] -> dst [BH][64][2048]
__global__ __launch_bounds__(256) void transpose_v_bf16(
    const short* __restrict__ src, short* __restrict__ dst) {
    __shared__ short tile[32][34];
    const int bh = blockIdx.z;
    src += (size_t)bh * 2048 * 64;
    dst += (size_t)bh * 2048 * 64;
    const int c0 = blockIdx.x * 32;   // hd
    const int r0 = blockIdx.y * 32;   // s
    const int tx = threadIdx.x & 31, ty = threadIdx.x >> 5;
#pragma unroll
    for (int i = 0; i < 32; i += 8)
        tile[ty + i][tx] = src[(size_t)(r0 + ty + i) * 64 + c0 + tx];
    __syncthreads();
#pragma unroll
    for (int i = 0; i < 32; i += 8)
        dst[(size_t)(c0 + ty + i) * 2048 + r0 + tx] = tile[tx][ty + i];
}

// ---------------- concat q/k/v bias into [3072] f32
__global__ __launch_bounds__(256) void concat_bias(
    const float* __restrict__ bq, const float* __restrict__ bk,
    const float* __restrict__ bv, float* __restrict__ o) {
    int i = blockIdx.x * 256 + threadIdx.x;
    if (i < 1024)      o[i] = bq[i];
    else if (i < 2048) o[i] = bk[i - 1024];
    else if (i < 3072) o[i] = bv[i - 2048];
}

// ---------------- LayerNorm (D=1024) f32 in -> bf16 out. 1 block/row, 256 thr
__global__ __launch_bounds__(256) void ln_bf16(
    const float* __restrict__ x, const float* __restrict__ gamma,
    const float* __restrict__ beta, short* __restrict__ out) {
    __shared__ float red[8];
    const int row = blockIdx.x, tid = threadIdx.x;
    const float4 v = *(const float4*)(x + (size_t)row * 1024 + tid * 4);
    float s = v.x + v.y + v.z + v.w;
    float q = v.x * v.x + v.y * v.y + v.z * v.z + v.w * v.w;
#pragma unroll
    for (int off = 32; off > 0; off >>= 1) {
        s += __shfl_xor(s, off);
        q += __shfl_xor(q, off);
    }
    if ((tid & 63) == 0) { red[(tid >> 6) * 2] = s; red[(tid >> 6) * 2 + 1] = q; }
    __syncthreads();
    s = red[0] + red[2] + red[4] + red[6];
    q = red[1] + red[3] + red[5] + red[7];
    const float mu = s * (1.0f / 1024.0f);
    const float var = q * (1.0f / 1024.0f) - mu * mu;
    const float rs = rsqrtf(var + 1e-5f);
    const float4 g  = *(const float4*)(gamma + tid * 4);
    const float4 bt = *(const float4*)(beta + tid * 4);
    short4 o;
    o.x = f2b((v.x - mu) * rs * g.x + bt.x);
    o.y = f2b((v.y - mu) * rs * g.y + bt.y);
    o.z = f2b((v.z - mu) * rs * g.z + bt.z);
    o.w = f2b((v.w - mu) * rs * g.w + bt.w);
    *(short4*)(out + (size_t)row * 1024 + tid * 4) = o;
}

// ---------------- bf16 MFMA GEMM: C[M,N] = A[M,K] * Bt[N,K]^T (+ epilogue)
template <int MODE>
__global__ __launch_bounds__(256) void gemm_bf16(
    const short* __restrict__ A, const short* __restrict__ Bt,
    const float* __restrict__ bias, const float* __restrict__ resid,
    float* __restrict__ outf, short* __restrict__ outb,
    int M, int N, int K) {
    __shared__ __align__(16) short As[128 * 32];
    __shared__ __align__(16) short Bs[128 * 32];

    const int tid = threadIdx.x;
    const int wave = tid >> 6, lane = tid & 63;
    const int l16 = lane & 15, quad = lane >> 4;
    const int wm = wave & 1, wn = wave >> 1;
    const int m0 = blockIdx.y * 128, n0 = blockIdx.x * 128;
    const int lrow = lane >> 2;
    const int lcol = (lane & 3) * 8;

    f32x4 acc[4][4] = {};

    for (int kk = 0; kk < K; kk += 32) {
#pragma unroll
        for (int i = 0; i < 2; ++i) {
            const int r = wave * 32 + i * 16 + lrow;
            const short* ga = A + (size_t)(m0 + r) * K + kk + lcol;
            short* la = &As[(wave * 32 + i * 16) * 32];
            __builtin_amdgcn_global_load_lds((g_void*)ga, (l_void*)la, 16, 0, 0);
            const short* gb = Bt + (size_t)(n0 + r) * K + kk + lcol;
            short* lb = &Bs[(wave * 32 + i * 16) * 32];
            __builtin_amdgcn_global_load_lds((g_void*)gb, (l_void*)lb, 16, 0, 0);
        }
        __syncthreads();
        s16x8 a[4], b[4];
#pragma unroll
        for (int t = 0; t < 4; ++t) {
            a[t] = *(const s16x8*)&As[(wm * 64 + t * 16 + l16) * 32 + quad * 8];
            b[t] = *(const s16x8*)&Bs[(wn * 64 + t * 16 + l16) * 32 + quad * 8];
        }
#pragma unroll
        for (int mt = 0; mt < 4; ++mt)
#pragma unroll
            for (int nt = 0; nt < 4; ++nt)
                acc[mt][nt] = mfma16(a[mt], b[nt], acc[mt][nt]);
        __syncthreads();
    }

#pragma unroll
    for (int mt = 0; mt < 4; ++mt) {
#pragma unroll
        for (int nt = 0; nt < 4; ++nt) {
            const int row = m0 + wm * 64 + mt * 16 + quad * 4;
            const int col = n0 + wn * 64 + nt * 16 + l16;
            const float bc = bias[col];
#pragma unroll
            for (int r = 0; r < 4; ++r) {
                float v = acc[mt][nt][r] + bc;
                const size_t rr = (size_t)(row + r);
                if (MODE == 0) {
                    const int sel = col >> 10, within = col & 1023;
                    const int h = within >> 6, hd = within & 63;
                    const size_t bidx = rr >> 11, sp = rr & 2047;
                    outb[(size_t)sel * (8192ull * 1024) +
                         ((bidx * 16 + h) * 2048 + sp) * 64 + hd] = f2b(v);
                } else if (MODE == 1) {
                    v += resid[rr * N + col];
                    outf[rr * N + col] = v;
                } else {
                    v = 0.5f * v * (1.0f + erff(v * 0.70710678118654752f));
                    outb[rr * (size_t)N + col] = f2b(v);
                }
            }
        }
    }
}

// ---------------- causal flash attention, S^T formulation
// Q,K bf16 [B,H,S,HD]; Vt bf16 [B,H,HD,S]; O bf16 [B,S,H*HD].
// Sᵀ = K·Qᵀ so each lane owns ONE softmax row q (= l16): in-lane reductions +
// 2 shfls; P exits in per-lane t-consecutive quads -> b64 LDS writes.
__global__ __launch_bounds__(256) void attn_kernel(
    const short* __restrict__ Q, const short* __restrict__ K,
    const short* __restrict__ Vt, short* __restrict__ O) {
    const int bid = blockIdx.x;
    const int p = bid & 15;
    const int h = (bid >> 4) & 15;
    const int b = bid >> 8;
    const int tid = threadIdx.x, wave = tid >> 6, lane = tid & 63;
    const int l16 = lane & 15, quad = lane >> 4;

    __shared__ __align__(16) short Ks[64 * 72];
    __shared__ __align__(16) short Vts[64 * 72];
    __shared__ __align__(16) short Ps[4][16 * 72];

    const size_t bh = ((size_t)b * 16 + h) * (2048ull * 64);
    const int srow = tid >> 2;          // 0..63
    const int sseg = (tid & 3) * 16;    // 0,16,32,48
    const float SC = 0.125f * 1.44269504088896f;   // 1/sqrt(64) * log2(e)

    for (int pass = 0; pass < 2; ++pass) {
        const int qt = pass ? (31 - p) : p;
        const int q0 = qt * 64;
        const int q_lane = q0 + wave * 16 + l16;   // this lane's softmax row

        const short* qrow = Q + bh + (size_t)q_lane * 64;
        s16x8 bq0 = *(const s16x8*)(qrow + quad * 8);
        s16x8 bq1 = *(const s16x8*)(qrow + 32 + quad * 8);

        f32x4 oacc[4] = {};               // rows q_local=quad*4+r, cols hd strip
        float mrow = -1e30f, lsum = 0.0f; // per softmax row q = q_lane

        for (int j = 0; j <= qt; ++j) {
            // issue global loads for this tile before the barrier
            const short* kg = K + bh + (size_t)(j * 64 + srow) * 64 + sseg;
            s16x8 k0 = *(const s16x8*)kg;
            s16x8 k1 = *(const s16x8*)(kg + 8);
            const short* vg = Vt + bh + (size_t)srow * 2048 + j * 64 + sseg;
            s16x8 v0 = *(const s16x8*)vg;
            s16x8 v1 = *(const s16x8*)(vg + 8);
            __syncthreads();
            *(s16x8*)&Ks[srow * 72 + sseg]      = k0;
            *(s16x8*)&Ks[srow * 72 + sseg + 8]  = k1;
            *(s16x8*)&Vts[srow * 72 + sseg]     = v0;
            *(s16x8*)&Vts[srow * 72 + sseg + 8] = v1;
            __syncthreads();

            // S^T = K·Qᵀ: st[s][r] = S[q=l16][t = j*64 + s*16 + quad*4 + r]
            f32x4 st[4];
#pragma unroll
            for (int s = 0; s < 4; ++s) {
                s16x8 ak0 = *(const s16x8*)&Ks[(s * 16 + l16) * 72 + quad * 8];
                s16x8 ak1 = *(const s16x8*)&Ks[(s * 16 + l16) * 72 + 32 + quad * 8];
                f32x4 c = {};
                c = mfma16(ak0, bq0, c);
                c = mfma16(ak1, bq1, c);
                st[s] = c;
            }
            // scale (+ causal mask, diagonal tile only)
            if (j == qt) {
#pragma unroll
                for (int s = 0; s < 4; ++s)
#pragma unroll
                    for (int r = 0; r < 4; ++r) {
                        const int t = j * 64 + s * 16 + quad * 4 + r;
                        st[s][r] = (t <= q_lane) ? st[s][r] * SC : -1e30f;
                    }
            } else {
#pragma unroll
                for (int s = 0; s < 4; ++s)
#pragma unroll
                    for (int r = 0; r < 4; ++r) st[s][r] *= SC;
            }
            // row max: in-lane over 16, then across quads (2 shfls)
            float m0v = fmaxf(fmaxf(st[0][0], st[0][1]), fmaxf(st[0][2], st[0][3]));
            float m1v = fmaxf(fmaxf(st[1][0], st[1][1]), fmaxf(st[1][2], st[1][3]));
            float m2v = fmaxf(fmaxf(st[2][0], st[2][1]), fmaxf(st[2][2], st[2][3]));
            float m3v = fmaxf(fmaxf(st[3][0], st[3][1]), fmaxf(st[3][2], st[3][3]));
            float mx = fmaxf(fmaxf(m0v, m1v), fmaxf(m2v, m3v));
            mx = fmaxf(mx, __shfl_xor(mx, 16));
            mx = fmaxf(mx, __shfl_xor(mx, 32));

            const float mn = fmaxf(mrow, mx);
            const float alpha = exp2f(mrow - mn);
            mrow = mn;

            // exp (base-2) + P write (b64 per strip) + row sum
            float rs = 0.0f;
#pragma unroll
            for (int s = 0; s < 4; ++s) {
#pragma unroll
                for (int r = 0; r < 4; ++r) {
                    st[s][r] = exp2f(st[s][r] - mn);
                    rs += st[s][r];
                }
                int2 pw;
                pw.x = pk2(st[s][0], st[s][1]);
                pw.y = pk2(st[s][2], st[s][3]);
                *(int2*)&Ps[wave][l16 * 72 + s * 16 + quad * 4] = pw;
            }
            rs += __shfl_xor(rs, 16);
            rs += __shfl_xor(rs, 32);
            lsum = lsum * alpha + rs;

            // broadcast alpha from softmax-row domain (l16) to oacc-row domain
            float ar[4];
#pragma unroll
            for (int r = 0; r < 4; ++r) ar[r] = __shfl(alpha, quad * 4 + r, 64);
#pragma unroll
            for (int nt = 0; nt < 4; ++nt)
#pragma unroll
                for (int r = 0; r < 4; ++r) oacc[nt][r] *= ar[r];

            // read P as A-operand fragments (per-wave region, no x-wave sync)
            asm volatile("s_waitcnt lgkmcnt(0)" ::: "memory");
            s16x8 ap0 = *(const s16x8*)&Ps[wave][l16 * 72 + quad * 8];
            s16x8 ap1 = *(const s16x8*)&Ps[wave][l16 * 72 + 32 + quad * 8];

            // O += P V
#pragma unroll
            for (int nt = 0; nt < 4; ++nt) {
                s16x8 bv0 = *(const s16x8*)&Vts[(nt * 16 + l16) * 72 + quad * 8];
                s16x8 bv1 = *(const s16x8*)&Vts[(nt * 16 + l16) * 72 + 32 + quad * 8];
                oacc[nt] = mfma16(ap0, bv0, oacc[nt]);
                oacc[nt] = mfma16(ap1, bv1, oacc[nt]);
            }
        }
        __syncthreads();   // protect LDS before next pass restages

        // epilogue: O[b, s, h*64+hd] bf16; lsum lives in l16 domain -> shfl
        float inv[4];
#pragma unroll
        for (int r = 0; r < 4; ++r)
            inv[r] = 1.0f / __shfl(lsum, quad * 4 + r, 64);
#pragma unroll
        for (int nt = 0; nt < 4; ++nt)
#pragma unroll
            for (int r = 0; r < 4; ++r) {
                const int row = q0 + wave * 16 + quad * 4 + r;
                O[((size_t)b * 2048 + row) * 1024 + h * 64 + nt * 16 + l16] =
                    f2b(oacc[nt][r] * inv[r]);
            }
    }
}

extern "C" void kernel_launch(void* const* d_in, const int* in_sizes, int n_in,
                              void* d_out, int out_size, void* d_ws, size_t ws_size,
                              hipStream_t stream) {
    const float* x     = (const float*)d_in[0];
    const float* Wq    = (const float*)d_in[1];
    const float* Wk    = (const float*)d_in[2];
    const float* Wv    = (const float*)d_in[3];
    const float* bq    = (const float*)d_in[4];
    const float* bk    = (const float*)d_in[5];
    const float* bv    = (const float*)d_in[6];
    const float* Wo    = (const float*)d_in[7];
    const float* bo    = (const float*)d_in[8];
    const float* W1    = (const float*)d_in[9];
    const float* b1    = (const float*)d_in[10];
    const float* W2    = (const float*)d_in[11];
    const float* b2    = (const float*)d_in[12];
    const float* gamma = (const float*)d_in[13];
    const float* beta  = (const float*)d_in[14];
    float* out = (float*)d_out;

    char* ws = (char*)d_ws;
    size_t off = 0;
    auto alloc = [&](size_t bytes) -> char* {
        char* p = ws + off;
        off += (bytes + 255) & ~(size_t)255;
        return p;
    };
    short* h1    = (short*)alloc(8192ull * 1024 * 2);
    short* btqkv = (short*)alloc(3072ull * 1024 * 2);
    short* btwo  = (short*)alloc(1024ull * 1024 * 2);
    short* btw1  = (short*)alloc(4096ull * 1024 * 2);
    short* btw2  = (short*)alloc(1024ull * 4096 * 2);
    float* bqkv  = (float*)alloc(3072ull * 4);
    short* qkv   = (short*)alloc(3ull * 8192 * 1024 * 2);
    short* vt    = (short*)alloc(8192ull * 1024 * 2);
    short* aout  = (short*)alloc(8192ull * 1024 * 2);
    float* x2    = (float*)alloc(8192ull * 1024 * 4);
    short* h2    = (short*)alloc(8192ull * 1024 * 2);
    short* m1    = (short*)alloc(8192ull * 4096 * 2);

    // weight prep
    transpose_bf16<<<dim3(2, 32, 16), 256, 0, stream>>>(Wq, btqkv, 1024, 64);
    transpose_bf16<<<dim3(2, 32, 16), 256, 0, stream>>>(Wk, btqkv + 1024ull * 1024, 1024, 64);
    transpose_bf16<<<dim3(2, 32, 16), 256, 0, stream>>>(Wv, btqkv + 2ull * 1024 * 1024, 1024, 64);
    transpose_bf16<<<dim3(32, 32, 1), 256, 0, stream>>>(Wo, btwo, 1024, 1024);
    transpose_bf16<<<dim3(128, 32, 1), 256, 0, stream>>>(W1, btw1, 1024, 4096);
    transpose_bf16<<<dim3(32, 128, 1), 256, 0, stream>>>(W2, btw2, 4096, 1024);
    concat_bias<<<12, 256, 0, stream>>>(bq, bk, bv, bqkv);

    // LN1
    ln_bf16<<<8192, 256, 0, stream>>>(x, gamma, beta, h1);
    // QKV projection
    gemm_bf16<0><<<dim3(24, 64), 256, 0, stream>>>(
        h1, btqkv, bqkv, nullptr, nullptr, qkv, 8192, 3072, 1024);
    // V -> Vt [B,H,HD,S]
    transpose_v_bf16<<<dim3(2, 64, 64), 256, 0, stream>>>(
        qkv + 2ull * 8192 * 1024, vt);
    // attention
    attn_kernel<<<1024, 256, 0, stream>>>(
        qkv, qkv + 8192ull * 1024, vt, aout);
    // Wo + residual -> x2 (f32)
    gemm_bf16<1><<<dim3(8, 64), 256, 0, stream>>>(
        aout, btwo, bo, x, x2, nullptr, 8192, 1024, 1024);
    // LN2
    ln_bf16<<<8192, 256, 0, stream>>>(x2, gamma, beta, h2);
    // MLP1 + GELU
    gemm_bf16<2><<<dim3(32, 64), 256, 0, stream>>>(
        h2, btw1, b1, nullptr, nullptr, m1, 8192, 4096, 1024);
    // MLP2 + residual -> out (f32)
    gemm_bf16<1><<<dim3(8, 64), 256, 0, stream>>>(
        m1, btw2, b2, x2, out, nullptr, 8192, 1024, 4096);
}